// Round 4
// baseline (792.487 us; speedup 1.0000x reference)
//
#include <hip/hip_runtime.h>

#define N_NODES 100000
#define N_EDGES 1600000
#define NFEAT 128
#define NHID 64
#define NCLASS 16

#define NPB 196                    // dst-nodes per bucket
#define NB 511                     // ceil(N_NODES / NPB)
#define HIST_EPT 16                // edges per thread, histA
#define HIST_BLOCKS ((N_EDGES + 256 * HIST_EPT - 1) / (256 * HIST_EPT))  // 391
#define FILL_EPT 8                 // edges per thread, fillA
#define FILL_BLOCKS ((N_EDGES + 256 * FILL_EPT - 1) / (256 * FILL_EPT))  // 782

typedef unsigned int u32;

__device__ __forceinline__ u32 pack_bf16(float a, float b) {
    u32 ua = __float_as_uint(a);
    u32 ub = __float_as_uint(b);
    ua = (ua + 0x7fffu + ((ua >> 16) & 1u)) >> 16;
    ub = (ub + 0x7fffu + ((ub >> 16) & 1u)) >> 16;
    return ua | (ub << 16);
}
__device__ __forceinline__ float bf16_lo(u32 u) { return __uint_as_float(u << 16); }
__device__ __forceinline__ float bf16_hi(u32 u) { return __uint_as_float(u & 0xffff0000u); }

// ---------- edge-index dtype detection (int64 ref vs int32 harness) ----------
__global__ void detect_kernel(const u32* __restrict__ ei, int* __restrict__ flag) {
    __shared__ int any_nz;
    if (threadIdx.x == 0) any_nz = 0;
    __syncthreads();
    u32 v = ei[2 * threadIdx.x + 1];
    if (v != 0) any_nz = 1;
    __syncthreads();
    if (threadIdx.x == 0) *flag = any_nz;  // 1 => int32 data, 0 => int64 data
}

__device__ __forceinline__ int load_idx(const void* ei, int flag, size_t pos) {
    return flag ? ((const int*)ei)[pos] : (int)((const long long*)ei)[pos];
}

// ---------- coarse binning: LDS-privatized histogram over NB buckets ----------
__global__ __launch_bounds__(256) void histA_kernel(const void* __restrict__ ei,
                                                    const int* __restrict__ flag,
                                                    int* __restrict__ ghist) {
    __shared__ int cnt[512];
    int t = threadIdx.x;
    cnt[t] = 0;
    cnt[t + 256] = 0;
    __syncthreads();
    int f = *flag;
    int base = blockIdx.x * 256 * HIST_EPT;
#pragma unroll
    for (int k = 0; k < HIST_EPT; ++k) {
        int e = base + k * 256 + t;
        if (e < N_EDGES) {
            int d = load_idx(ei, f, (size_t)N_EDGES + e);
            atomicAdd(&cnt[d / NPB], 1);
        }
    }
    __syncthreads();
    if (cnt[t] > 0) atomicAdd(&ghist[t], cnt[t]);
    if (cnt[t + 256] > 0) atomicAdd(&ghist[t + 256], cnt[t + 256]);
}

// single-block scan of NB bucket counts -> bstart (exclusive) + gcursor
__global__ __launch_bounds__(512) void scanA_kernel(const int* __restrict__ ghist,
                                                    int* __restrict__ bstart,
                                                    int* __restrict__ gcursor) {
    __shared__ int lds[512];
    int t = threadIdx.x;
    int own = (t < NB) ? ghist[t] : 0;
    lds[t] = own;
    __syncthreads();
    for (int off = 1; off < 512; off <<= 1) {
        int v = (t >= off) ? lds[t - off] : 0;
        __syncthreads();
        lds[t] += v;
        __syncthreads();
    }
    int excl = lds[t] - own;
    bstart[t] = excl;
    if (t == 511) bstart[512] = lds[511];
    if (t < NB) gcursor[t] = excl;
}

// block-privatized bin scatter: {src | dstl<<20, w} into bucket-contiguous ebuf
__global__ __launch_bounds__(256) void fillA_kernel(const void* __restrict__ ei,
                                                    const int* __restrict__ flag,
                                                    const float* __restrict__ ew,
                                                    int* __restrict__ gcursor,
                                                    int2* __restrict__ ebuf) {
    __shared__ int cnt[512];
    __shared__ int base[512];
    int t = threadIdx.x;
    cnt[t] = 0;
    cnt[t + 256] = 0;
    __syncthreads();
    int f = *flag;
    int eb = blockIdx.x * 256 * FILL_EPT;
    int src[FILL_EPT], bin[FILL_EPT], rank[FILL_EPT];
    float w[FILL_EPT];
#pragma unroll
    for (int k = 0; k < FILL_EPT; ++k) {
        int e = eb + k * 256 + t;
        bin[k] = -1;
        if (e < N_EDGES) {
            int s = load_idx(ei, f, (size_t)e);
            int d = load_idx(ei, f, (size_t)N_EDGES + e);
            int b = d / NPB;
            src[k] = s | ((d - b * NPB) << 20);
            w[k] = ew[e];
            bin[k] = b;
            rank[k] = atomicAdd(&cnt[b], 1);
        }
    }
    __syncthreads();
    if (cnt[t] > 0) base[t] = atomicAdd(&gcursor[t], cnt[t]);
    if (cnt[t + 256] > 0) base[t + 256] = atomicAdd(&gcursor[t + 256], cnt[t + 256]);
    __syncthreads();
#pragma unroll
    for (int k = 0; k < FILL_EPT; ++k) {
        if (bin[k] >= 0) {
            int pos = base[bin[k]] + rank[k];
            ebuf[pos] = make_int2(src[k], __float_as_int(w[k]));
        }
    }
}

// ---------- dense row GEMMs (W staged in LDS, 1 row per thread) ----------
__global__ __launch_bounds__(256) void gemm1_kernel(const float* __restrict__ X,
                                                    const float* __restrict__ W,
                                                    u32* __restrict__ Y) {
    __shared__ float Ws[NFEAT * NHID];  // 32 KB
    for (int i = threadIdx.x; i < NFEAT * NHID; i += 256) Ws[i] = W[i];
    __syncthreads();
    int row = blockIdx.x * 256 + threadIdx.x;
    if (row >= N_NODES) return;
    float acc[NHID];
#pragma unroll
    for (int j = 0; j < NHID; ++j) acc[j] = 0.f;
    const float* xr = X + (size_t)row * NFEAT;
    for (int k = 0; k < NFEAT; k += 4) {
        float4 xv = *(const float4*)(xr + k);
#pragma unroll
        for (int j = 0; j < NHID; ++j) {
            acc[j] += xv.x * Ws[(k + 0) * NHID + j];
            acc[j] += xv.y * Ws[(k + 1) * NHID + j];
            acc[j] += xv.z * Ws[(k + 2) * NHID + j];
            acc[j] += xv.w * Ws[(k + 3) * NHID + j];
        }
    }
    u32* yr = Y + (size_t)row * (NHID / 2);
#pragma unroll
    for (int m = 0; m < NHID / 2; m += 4) {
        uint4 o;
        o.x = pack_bf16(acc[2 * m + 0], acc[2 * m + 1]);
        o.y = pack_bf16(acc[2 * m + 2], acc[2 * m + 3]);
        o.z = pack_bf16(acc[2 * m + 4], acc[2 * m + 5]);
        o.w = pack_bf16(acc[2 * m + 6], acc[2 * m + 7]);
        *(uint4*)(yr + m) = o;
    }
}

__global__ __launch_bounds__(256) void gemm2_kernel(const float* __restrict__ H,
                                                    const float* __restrict__ W,
                                                    u32* __restrict__ Y) {
    __shared__ float Ws[NHID * NCLASS];  // 4 KB
    for (int i = threadIdx.x; i < NHID * NCLASS; i += 256) Ws[i] = W[i];
    __syncthreads();
    int row = blockIdx.x * 256 + threadIdx.x;
    if (row >= N_NODES) return;
    float acc[NCLASS];
#pragma unroll
    for (int j = 0; j < NCLASS; ++j) acc[j] = 0.f;
    const float* hr = H + (size_t)row * NHID;
    for (int k = 0; k < NHID; k += 4) {
        float4 hv = *(const float4*)(hr + k);
#pragma unroll
        for (int j = 0; j < NCLASS; ++j) {
            acc[j] += hv.x * Ws[(k + 0) * NCLASS + j];
            acc[j] += hv.y * Ws[(k + 1) * NCLASS + j];
            acc[j] += hv.z * Ws[(k + 2) * NCLASS + j];
            acc[j] += hv.w * Ws[(k + 3) * NCLASS + j];
        }
    }
    u32* yr = Y + (size_t)row * (NCLASS / 2);
    uint4 o0, o1;
    o0.x = pack_bf16(acc[0], acc[1]);
    o0.y = pack_bf16(acc[2], acc[3]);
    o0.z = pack_bf16(acc[4], acc[5]);
    o0.w = pack_bf16(acc[6], acc[7]);
    o1.x = pack_bf16(acc[8], acc[9]);
    o1.y = pack_bf16(acc[10], acc[11]);
    o1.z = pack_bf16(acc[12], acc[13]);
    o1.w = pack_bf16(acc[14], acc[15]);
    *(uint4*)(yr + 0) = o0;
    *(uint4*)(yr + 4) = o1;
}

// ---------- bucketed aggregation: LDS f32 accumulator, no global atomics ----------
// Layer 1: one block per bucket; half-wave (32 lanes) per edge, lane = 2 feats;
// 2-deep edge unroll; relu fused into coalesced write of h.
__global__ __launch_bounds__(256) void agg1_kernel(const u32* __restrict__ xwb,
                                                   const int* __restrict__ bstart,
                                                   const int2* __restrict__ ebuf,
                                                   float* __restrict__ h) {
    __shared__ float acc[NPB * NHID];  // 49 KB
    int t = threadIdx.x;
    int b = blockIdx.x;
    for (int i = t; i < NPB * NHID; i += 256) acc[i] = 0.f;
    __syncthreads();
    int start = bstart[b], end = bstart[b + 1];
    int hw = t >> 5;
    int ln = t & 31;
    int i = start + hw * 2;
    for (; i + 1 < end; i += 16) {
        int2 p0 = ebuf[i];
        int2 p1 = ebuf[i + 1];
        int s0 = p0.x & 0xFFFFF, d0 = p0.x >> 20;
        int s1 = p1.x & 0xFFFFF, d1 = p1.x >> 20;
        u32 u0 = xwb[(size_t)s0 * 32 + ln];
        u32 u1 = xwb[(size_t)s1 * 32 + ln];
        float w0 = __int_as_float(p0.y);
        float w1 = __int_as_float(p1.y);
        atomicAdd(&acc[d0 * NHID + 2 * ln + 0], w0 * bf16_lo(u0));
        atomicAdd(&acc[d0 * NHID + 2 * ln + 1], w0 * bf16_hi(u0));
        atomicAdd(&acc[d1 * NHID + 2 * ln + 0], w1 * bf16_lo(u1));
        atomicAdd(&acc[d1 * NHID + 2 * ln + 1], w1 * bf16_hi(u1));
    }
    if (i < end) {
        int2 p0 = ebuf[i];
        int s0 = p0.x & 0xFFFFF, d0 = p0.x >> 20;
        u32 u0 = xwb[(size_t)s0 * 32 + ln];
        float w0 = __int_as_float(p0.y);
        atomicAdd(&acc[d0 * NHID + 2 * ln + 0], w0 * bf16_lo(u0));
        atomicAdd(&acc[d0 * NHID + 2 * ln + 1], w0 * bf16_hi(u0));
    }
    __syncthreads();
    for (int idx = t; idx < NPB * NHID; idx += 256) {
        int node = b * NPB + (idx >> 6);
        if (node < N_NODES) h[(size_t)node * NHID + (idx & 63)] = fmaxf(acc[idx], 0.f);
    }
}

// Layer 2: one block per bucket; 8 lanes per edge (lane = 2 feats of 16).
__global__ __launch_bounds__(256) void agg2_kernel(const u32* __restrict__ hwb,
                                                   const int* __restrict__ bstart,
                                                   const int2* __restrict__ ebuf,
                                                   float* __restrict__ out) {
    __shared__ float acc[NPB * NCLASS];  // 12.25 KB
    int t = threadIdx.x;
    int b = blockIdx.x;
    for (int i = t; i < NPB * NCLASS; i += 256) acc[i] = 0.f;
    __syncthreads();
    int start = bstart[b], end = bstart[b + 1];
    int ln = t & 7;
    for (int i = start + (t >> 3); i < end; i += 32) {
        int2 p = ebuf[i];
        int s = p.x & 0xFFFFF, d = p.x >> 20;
        u32 u = hwb[(size_t)s * 8 + ln];
        float w = __int_as_float(p.y);
        atomicAdd(&acc[d * NCLASS + 2 * ln + 0], w * bf16_lo(u));
        atomicAdd(&acc[d * NCLASS + 2 * ln + 1], w * bf16_hi(u));
    }
    __syncthreads();
    for (int idx = t; idx < NPB * NCLASS; idx += 256) {
        int node = b * NPB + (idx >> 4);
        if (node < N_NODES) out[(size_t)node * NCLASS + (idx & 15)] = acc[idx];
    }
}

extern "C" void kernel_launch(void* const* d_in, const int* in_sizes, int n_in,
                              void* d_out, int out_size, void* d_ws, size_t ws_size,
                              hipStream_t stream) {
    const float* x  = (const float*)d_in[0];
    const void*  ei = d_in[1];
    const float* ew = (const float*)d_in[2];
    const float* W1 = (const float*)d_in[3];
    const float* W2 = (const float*)d_in[4];
    float* out = (float*)d_out;

    char* ws = (char*)d_ws;
    size_t off = 0;
    auto take = [&](size_t bytes) {
        char* p = ws + off;
        off += (bytes + 511) & ~(size_t)511;
        return p;
    };
    int*   flag    = (int*)take(4);
    int*   ghist   = (int*)take(512 * 4);
    int*   bstart  = (int*)take(513 * 4);
    int*   gcursor = (int*)take(512 * 4);
    int2*  ebuf    = (int2*)take((size_t)N_EDGES * 8);
    u32*   xwb     = (u32*)take((size_t)N_NODES * (NHID / 2) * 4);  // bf16 packed
    float* h       = (float*)take((size_t)N_NODES * NHID * 4);
    u32*   hwb     = xwb;  // reuse: xwb dead after agg1

    detect_kernel<<<1, 256, 0, stream>>>((const u32*)ei, flag);
    hipMemsetAsync(ghist, 0, 512 * 4, stream);
    histA_kernel<<<HIST_BLOCKS, 256, 0, stream>>>(ei, flag, ghist);
    scanA_kernel<<<1, 512, 0, stream>>>(ghist, bstart, gcursor);
    fillA_kernel<<<FILL_BLOCKS, 256, 0, stream>>>(ei, flag, ew, gcursor, ebuf);

    gemm1_kernel<<<(N_NODES + 255) / 256, 256, 0, stream>>>(x, W1, xwb);
    agg1_kernel<<<NB, 256, 0, stream>>>(xwb, bstart, ebuf, h);
    gemm2_kernel<<<(N_NODES + 255) / 256, 256, 0, stream>>>(h, W2, hwb);
    agg2_kernel<<<NB, 256, 0, stream>>>(hwb, bstart, ebuf, out);
}

// Round 5
// 208.915 us; speedup vs baseline: 3.7933x; 3.7933x over previous
//
#include <hip/hip_runtime.h>

#define N_NODES 100000
#define N_EDGES 1600000
#define NFEAT 128
#define NHID 64
#define NCLASS 16

#define NPB 196                    // dst-nodes per bucket
#define NB 511                     // ceil(N_NODES / NPB)
#define HIST_EPT 16
#define HIST_BLOCKS ((N_EDGES + 256 * HIST_EPT - 1) / (256 * HIST_EPT))  // 391
#define FILL_EPT 8
#define FILL_BLOCKS ((N_EDGES + 256 * FILL_EPT - 1) / (256 * FILL_EPT))  // 782
#define GR 64                      // gemm1 rows per block

typedef unsigned int u32;

__device__ __forceinline__ u32 pack_bf16(float a, float b) {
    u32 ua = __float_as_uint(a);
    u32 ub = __float_as_uint(b);
    ua = (ua + 0x7fffu + ((ua >> 16) & 1u)) >> 16;
    ub = (ub + 0x7fffu + ((ub >> 16) & 1u)) >> 16;
    return ua | (ub << 16);
}
__device__ __forceinline__ float bf16_lo(u32 u) { return __uint_as_float(u << 16); }
__device__ __forceinline__ float bf16_hi(u32 u) { return __uint_as_float(u & 0xffff0000u); }

// ---------- edge-index dtype detection (int64 ref vs int32 harness) ----------
__global__ void detect_kernel(const u32* __restrict__ ei, int* __restrict__ flag) {
    __shared__ int any_nz;
    if (threadIdx.x == 0) any_nz = 0;
    __syncthreads();
    u32 v = ei[2 * threadIdx.x + 1];
    if (v != 0) any_nz = 1;
    __syncthreads();
    if (threadIdx.x == 0) *flag = any_nz;  // 1 => int32 data, 0 => int64 data
}

__device__ __forceinline__ int load_idx(const void* ei, int flag, size_t pos) {
    return flag ? ((const int*)ei)[pos] : (int)((const long long*)ei)[pos];
}

// ---------- coarse binning: LDS-privatized histogram over NB buckets ----------
__global__ __launch_bounds__(256) void histA_kernel(const void* __restrict__ ei,
                                                    const int* __restrict__ flag,
                                                    int* __restrict__ ghist) {
    __shared__ int cnt[512];
    int t = threadIdx.x;
    cnt[t] = 0;
    cnt[t + 256] = 0;
    __syncthreads();
    int f = *flag;
    int base = blockIdx.x * 256 * HIST_EPT;
#pragma unroll
    for (int k = 0; k < HIST_EPT; ++k) {
        int e = base + k * 256 + t;
        if (e < N_EDGES) {
            int d = load_idx(ei, f, (size_t)N_EDGES + e);
            atomicAdd(&cnt[d / NPB], 1);
        }
    }
    __syncthreads();
    if (cnt[t] > 0) atomicAdd(&ghist[t], cnt[t]);
    if (cnt[t + 256] > 0) atomicAdd(&ghist[t + 256], cnt[t + 256]);
}

// single-block scan of NB bucket counts -> bstart (exclusive) + gcursor
__global__ __launch_bounds__(512) void scanA_kernel(const int* __restrict__ ghist,
                                                    int* __restrict__ bstart,
                                                    int* __restrict__ gcursor) {
    __shared__ int lds[512];
    int t = threadIdx.x;
    int own = (t < NB) ? ghist[t] : 0;
    lds[t] = own;
    __syncthreads();
    for (int off = 1; off < 512; off <<= 1) {
        int v = (t >= off) ? lds[t - off] : 0;
        __syncthreads();
        lds[t] += v;
        __syncthreads();
    }
    int excl = lds[t] - own;
    bstart[t] = excl;  // bstart[511] == N_EDGES (own=0 there)
    if (t == 511) bstart[512] = lds[511];
    if (t < NB) gcursor[t] = excl;
}

// block-privatized bin scatter: {src | dstl<<20, w} into bucket-contiguous ebuf
__global__ __launch_bounds__(256) void fillA_kernel(const void* __restrict__ ei,
                                                    const int* __restrict__ flag,
                                                    const float* __restrict__ ew,
                                                    int* __restrict__ gcursor,
                                                    int2* __restrict__ ebuf) {
    __shared__ int cnt[512];
    __shared__ int base[512];
    int t = threadIdx.x;
    cnt[t] = 0;
    cnt[t + 256] = 0;
    __syncthreads();
    int f = *flag;
    int eb = blockIdx.x * 256 * FILL_EPT;
    int src[FILL_EPT], bin[FILL_EPT], rank[FILL_EPT];
    float w[FILL_EPT];
#pragma unroll
    for (int k = 0; k < FILL_EPT; ++k) {
        int e = eb + k * 256 + t;
        bin[k] = -1;
        if (e < N_EDGES) {
            int s = load_idx(ei, f, (size_t)e);
            int d = load_idx(ei, f, (size_t)N_EDGES + e);
            int b = d / NPB;
            src[k] = s | ((d - b * NPB) << 20);
            w[k] = ew[e];
            bin[k] = b;
            rank[k] = atomicAdd(&cnt[b], 1);
        }
    }
    __syncthreads();
    if (cnt[t] > 0) base[t] = atomicAdd(&gcursor[t], cnt[t]);
    if (cnt[t + 256] > 0) base[t + 256] = atomicAdd(&gcursor[t + 256], cnt[t + 256]);
    __syncthreads();
#pragma unroll
    for (int k = 0; k < FILL_EPT; ++k) {
        if (bin[k] >= 0) {
            int pos = base[bin[k]] + rank[k];
            ebuf[pos] = make_int2(src[k], __float_as_int(w[k]));
        }
    }
}

// per-bucket counting sort -> exact CSR (ebuf2) + row_ptr; all writes stay in
// the bucket's contiguous ~25KB window (L2-resident, full-line writes)
__global__ __launch_bounds__(256) void sortB_kernel(const int2* __restrict__ ebuf,
                                                    const int* __restrict__ bstart,
                                                    int2* __restrict__ ebuf2,
                                                    int* __restrict__ row_ptr) {
    __shared__ int cnt[NPB];
    __shared__ int sc[256];
    __shared__ int cur[NPB];
    int t = threadIdx.x, b = blockIdx.x;
    for (int i = t; i < NPB; i += 256) cnt[i] = 0;
    __syncthreads();
    int start = bstart[b], end = bstart[b + 1];
    for (int i = start + t; i < end; i += 256) {
        int dl = ((u32)ebuf[i].x) >> 20;
        atomicAdd(&cnt[dl], 1);
    }
    __syncthreads();
    int own = (t < NPB) ? cnt[t] : 0;
    sc[t] = own;
    __syncthreads();
    for (int off = 1; off < 256; off <<= 1) {
        int v = (t >= off) ? sc[t - off] : 0;
        __syncthreads();
        sc[t] += v;
        __syncthreads();
    }
    int excl = sc[t] - own;
    if (t < NPB) {
        cur[t] = excl;
        int node = b * NPB + t;
        if (node < N_NODES) row_ptr[node] = start + excl;
    }
    if (b == 0 && t == 0) row_ptr[N_NODES] = N_EDGES;
    __syncthreads();
    for (int i = start + t; i < end; i += 256) {
        int2 p = ebuf[i];
        int dl = ((u32)p.x) >> 20;
        int pos = start + atomicAdd(&cur[dl], 1);
        ebuf2[pos] = make_int2(p.x & 0xFFFFF, p.y);
    }
}

// ---------- gemm1: LDS-tiled 64x64x128, coalesced X staging ----------
__global__ __launch_bounds__(256) void gemm1_kernel(const float* __restrict__ X,
                                                    const float* __restrict__ W,
                                                    u32* __restrict__ Y) {
    __shared__ float Wsh[NFEAT * NHID];  // 32 KB
    __shared__ float Xs[GR][33];         // 8.25 KB (pad 33 breaks 32-bank stride)
    int t = threadIdx.x;
    int rb = blockIdx.x * GR;
    for (int i = t; i < NFEAT * NHID; i += 256) Wsh[i] = W[i];
    float acc[4][4];
#pragma unroll
    for (int i = 0; i < 4; ++i)
#pragma unroll
        for (int j = 0; j < 4; ++j) acc[i][j] = 0.f;
    int r0 = (t >> 4) * 4;  // 16 row-groups * 4 rows
    int c0 = (t & 15) * 4;  // 16 col-groups * 4 cols
    for (int kk = 0; kk < NFEAT; kk += 32) {
        __syncthreads();  // also covers Wsh staging on first iteration
        for (int idx = t; idx < GR * 32; idx += 256) {
            int r = idx >> 5, c = idx & 31;
            int row = rb + r;
            Xs[r][c] = (row < N_NODES) ? X[(size_t)row * NFEAT + kk + c] : 0.f;
        }
        __syncthreads();
#pragma unroll
        for (int k = 0; k < 32; ++k) {
            float x0 = Xs[r0 + 0][k];
            float x1 = Xs[r0 + 1][k];
            float x2 = Xs[r0 + 2][k];
            float x3 = Xs[r0 + 3][k];
            const float* wr = &Wsh[(kk + k) * NHID + c0];
            float w0 = wr[0], w1 = wr[1], w2 = wr[2], w3 = wr[3];
            acc[0][0] += x0 * w0; acc[0][1] += x0 * w1; acc[0][2] += x0 * w2; acc[0][3] += x0 * w3;
            acc[1][0] += x1 * w0; acc[1][1] += x1 * w1; acc[1][2] += x1 * w2; acc[1][3] += x1 * w3;
            acc[2][0] += x2 * w0; acc[2][1] += x2 * w1; acc[2][2] += x2 * w2; acc[2][3] += x2 * w3;
            acc[3][0] += x3 * w0; acc[3][1] += x3 * w1; acc[3][2] += x3 * w2; acc[3][3] += x3 * w3;
        }
    }
#pragma unroll
    for (int i = 0; i < 4; ++i) {
        int row = rb + r0 + i;
        if (row < N_NODES) {
            uint2 o;
            o.x = pack_bf16(acc[i][0], acc[i][1]);
            o.y = pack_bf16(acc[i][2], acc[i][3]);
            *(uint2*)(Y + (size_t)row * (NHID / 2) + (c0 >> 1)) = o;
        }
    }
}

// gemm2: h[N,64] fp32 @ W2[64,16] -> hwb packed bf16 [N, 8 u32]
__global__ __launch_bounds__(256) void gemm2_kernel(const float* __restrict__ H,
                                                    const float* __restrict__ W,
                                                    u32* __restrict__ Y) {
    __shared__ float Ws[NHID * NCLASS];  // 4 KB
    for (int i = threadIdx.x; i < NHID * NCLASS; i += 256) Ws[i] = W[i];
    __syncthreads();
    int row = blockIdx.x * 256 + threadIdx.x;
    if (row >= N_NODES) return;
    float acc[NCLASS];
#pragma unroll
    for (int j = 0; j < NCLASS; ++j) acc[j] = 0.f;
    const float* hr = H + (size_t)row * NHID;
    for (int k = 0; k < NHID; k += 4) {
        float4 hv = *(const float4*)(hr + k);
#pragma unroll
        for (int j = 0; j < NCLASS; ++j) {
            acc[j] += hv.x * Ws[(k + 0) * NCLASS + j];
            acc[j] += hv.y * Ws[(k + 1) * NCLASS + j];
            acc[j] += hv.z * Ws[(k + 2) * NCLASS + j];
            acc[j] += hv.w * Ws[(k + 3) * NCLASS + j];
        }
    }
    u32* yr = Y + (size_t)row * (NCLASS / 2);
    uint4 o0, o1;
    o0.x = pack_bf16(acc[0], acc[1]);
    o0.y = pack_bf16(acc[2], acc[3]);
    o0.z = pack_bf16(acc[4], acc[5]);
    o0.w = pack_bf16(acc[6], acc[7]);
    o1.x = pack_bf16(acc[8], acc[9]);
    o1.y = pack_bf16(acc[10], acc[11]);
    o1.z = pack_bf16(acc[12], acc[13]);
    o1.w = pack_bf16(acc[14], acc[15]);
    *(uint4*)(yr + 0) = o0;
    *(uint4*)(yr + 4) = o1;
}

// ---------- CSR aggregation (round-3 form: edge-parallel waves, no atomics) ----------
// Layer 1: half-wave (32 lanes) per node, lane owns 2 packed feats; 4-deep unroll.
__global__ __launch_bounds__(256) void agg1_kernel(const u32* __restrict__ xwb,
                                                   const int* __restrict__ row_ptr,
                                                   const int2* __restrict__ ep,
                                                   float* __restrict__ h) {
    int t = blockIdx.x * 256 + threadIdx.x;
    int node = t >> 5;
    int ln = t & 31;
    if (node >= N_NODES) return;
    int start = row_ptr[node], end = row_ptr[node + 1];
    float a0x = 0.f, a0y = 0.f, a1x = 0.f, a1y = 0.f;
    float a2x = 0.f, a2y = 0.f, a3x = 0.f, a3y = 0.f;
    int i = start;
    for (; i + 4 <= end; i += 4) {
        int2 p0 = ep[i + 0];
        int2 p1 = ep[i + 1];
        int2 p2 = ep[i + 2];
        int2 p3 = ep[i + 3];
        u32 u0 = xwb[(size_t)p0.x * 32 + ln];
        u32 u1 = xwb[(size_t)p1.x * 32 + ln];
        u32 u2 = xwb[(size_t)p2.x * 32 + ln];
        u32 u3 = xwb[(size_t)p3.x * 32 + ln];
        float w0 = __int_as_float(p0.y), w1 = __int_as_float(p1.y);
        float w2 = __int_as_float(p2.y), w3 = __int_as_float(p3.y);
        a0x += w0 * bf16_lo(u0); a0y += w0 * bf16_hi(u0);
        a1x += w1 * bf16_lo(u1); a1y += w1 * bf16_hi(u1);
        a2x += w2 * bf16_lo(u2); a2y += w2 * bf16_hi(u2);
        a3x += w3 * bf16_lo(u3); a3y += w3 * bf16_hi(u3);
    }
    for (; i < end; ++i) {
        int2 p0 = ep[i];
        u32 u0 = xwb[(size_t)p0.x * 32 + ln];
        float w0 = __int_as_float(p0.y);
        a0x += w0 * bf16_lo(u0); a0y += w0 * bf16_hi(u0);
    }
    float sx = (a0x + a1x) + (a2x + a3x);
    float sy = (a0y + a1y) + (a2y + a3y);
    *(float2*)(h + (size_t)node * NHID + 2 * ln) =
        make_float2(fmaxf(sx, 0.f), fmaxf(sy, 0.f));
}

// Layer 2: one wave per node; lane = sub*8 + p, 8 edges in flight, shfl reduce.
__global__ __launch_bounds__(256) void agg2_kernel(const u32* __restrict__ hwb,
                                                   const int* __restrict__ row_ptr,
                                                   const int2* __restrict__ ep,
                                                   float* __restrict__ out) {
    int t = blockIdx.x * 256 + threadIdx.x;
    int node = t >> 6;
    int lane = t & 63;
    int p = lane & 7;
    int sub = lane >> 3;
    if (node >= N_NODES) return;
    int start = row_ptr[node], end = row_ptr[node + 1];
    float ax = 0.f, ay = 0.f;
    for (int i = start + sub; i < end; i += 8) {
        int2 pr = ep[i];
        u32 u = hwb[(size_t)pr.x * 8 + p];
        float w = __int_as_float(pr.y);
        ax += w * bf16_lo(u);
        ay += w * bf16_hi(u);
    }
    ax += __shfl_xor(ax, 8, 64);  ay += __shfl_xor(ay, 8, 64);
    ax += __shfl_xor(ax, 16, 64); ay += __shfl_xor(ay, 16, 64);
    ax += __shfl_xor(ax, 32, 64); ay += __shfl_xor(ay, 32, 64);
    if (sub == 0) *(float2*)(out + (size_t)node * NCLASS + 2 * p) = make_float2(ax, ay);
}

extern "C" void kernel_launch(void* const* d_in, const int* in_sizes, int n_in,
                              void* d_out, int out_size, void* d_ws, size_t ws_size,
                              hipStream_t stream) {
    const float* x  = (const float*)d_in[0];
    const void*  ei = d_in[1];
    const float* ew = (const float*)d_in[2];
    const float* W1 = (const float*)d_in[3];
    const float* W2 = (const float*)d_in[4];
    float* out = (float*)d_out;

    char* ws = (char*)d_ws;
    size_t off = 0;
    auto take = [&](size_t bytes) {
        char* p = ws + off;
        off += (bytes + 511) & ~(size_t)511;
        return p;
    };
    int*   flag    = (int*)take(4);
    int*   ghist   = (int*)take(512 * 4);
    int*   bstart  = (int*)take(513 * 4);
    int*   gcursor = (int*)take(512 * 4);
    int*   row_ptr = (int*)take((size_t)(N_NODES + 1) * 4);
    int2*  ebuf    = (int2*)take((size_t)N_EDGES * 8);
    int2*  ebuf2   = (int2*)take((size_t)N_EDGES * 8);
    u32*   xwb     = (u32*)take((size_t)N_NODES * (NHID / 2) * 4);  // bf16 packed
    float* h       = (float*)take((size_t)N_NODES * NHID * 4);
    u32*   hwb     = xwb;  // reuse: xwb dead after agg1

    detect_kernel<<<1, 256, 0, stream>>>((const u32*)ei, flag);
    hipMemsetAsync(ghist, 0, 512 * 4, stream);
    histA_kernel<<<HIST_BLOCKS, 256, 0, stream>>>(ei, flag, ghist);
    scanA_kernel<<<1, 512, 0, stream>>>(ghist, bstart, gcursor);
    fillA_kernel<<<FILL_BLOCKS, 256, 0, stream>>>(ei, flag, ew, gcursor, ebuf);
    sortB_kernel<<<NB, 256, 0, stream>>>(ebuf, bstart, ebuf2, row_ptr);

    gemm1_kernel<<<(N_NODES + GR - 1) / GR, 256, 0, stream>>>(x, W1, xwb);
    agg1_kernel<<<(N_NODES * 32 + 255) / 256, 256, 0, stream>>>(xwb, row_ptr, ebuf2, h);
    gemm2_kernel<<<(N_NODES + 255) / 256, 256, 0, stream>>>(h, W2, hwb);
    agg2_kernel<<<(N_NODES * 64 + 255) / 256, 256, 0, stream>>>(hwb, row_ptr, ebuf2, out);
}

// Round 6
// 207.292 us; speedup vs baseline: 3.8230x; 1.0078x over previous
//
#include <hip/hip_runtime.h>

#define N_NODES 100000
#define N_EDGES 1600000
#define NFEAT 128
#define NHID 64
#define NCLASS 16

#define NPB 196                    // dst-nodes per bucket
#define NB 511                     // ceil(N_NODES / NPB)
#define HIST_EPT 16
#define HIST_BLOCKS ((N_EDGES + 256 * HIST_EPT - 1) / (256 * HIST_EPT))  // 391
#define FILL_EPT 8
#define FILL_BLOCKS ((N_EDGES + 256 * FILL_EPT - 1) / (256 * FILL_EPT))  // 782
#define GR 128                     // gemm1 rows per block (512 threads)

typedef unsigned int u32;

__device__ __forceinline__ u32 pack_bf16(float a, float b) {
    u32 ua = __float_as_uint(a);
    u32 ub = __float_as_uint(b);
    ua = (ua + 0x7fffu + ((ua >> 16) & 1u)) >> 16;
    ub = (ub + 0x7fffu + ((ub >> 16) & 1u)) >> 16;
    return ua | (ub << 16);
}
__device__ __forceinline__ float bf16_lo(u32 u) { return __uint_as_float(u << 16); }
__device__ __forceinline__ float bf16_hi(u32 u) { return __uint_as_float(u & 0xffff0000u); }

// ---------- edge-index dtype detection (int64 ref vs int32 harness) ----------
__global__ void detect_kernel(const u32* __restrict__ ei, int* __restrict__ flag) {
    __shared__ int any_nz;
    if (threadIdx.x == 0) any_nz = 0;
    __syncthreads();
    u32 v = ei[2 * threadIdx.x + 1];
    if (v != 0) any_nz = 1;
    __syncthreads();
    if (threadIdx.x == 0) *flag = any_nz;  // 1 => int32 data, 0 => int64 data
}

__device__ __forceinline__ int load_idx(const void* ei, int flag, size_t pos) {
    return flag ? ((const int*)ei)[pos] : (int)((const long long*)ei)[pos];
}

// ---------- coarse binning: LDS-privatized histogram over NB buckets ----------
__global__ __launch_bounds__(256) void histA_kernel(const void* __restrict__ ei,
                                                    const int* __restrict__ flag,
                                                    int* __restrict__ ghist) {
    __shared__ int cnt[512];
    int t = threadIdx.x;
    cnt[t] = 0;
    cnt[t + 256] = 0;
    __syncthreads();
    int f = *flag;
    int base = blockIdx.x * 256 * HIST_EPT;
#pragma unroll
    for (int k = 0; k < HIST_EPT; ++k) {
        int e = base + k * 256 + t;
        if (e < N_EDGES) {
            int d = load_idx(ei, f, (size_t)N_EDGES + e);
            atomicAdd(&cnt[d / NPB], 1);
        }
    }
    __syncthreads();
    if (cnt[t] > 0) atomicAdd(&ghist[t], cnt[t]);
    if (cnt[t + 256] > 0) atomicAdd(&ghist[t + 256], cnt[t + 256]);
}

// single-block scan of NB bucket counts -> bstart (exclusive) + gcursor
__global__ __launch_bounds__(512) void scanA_kernel(const int* __restrict__ ghist,
                                                    int* __restrict__ bstart,
                                                    int* __restrict__ gcursor) {
    __shared__ int lds[512];
    int t = threadIdx.x;
    int own = (t < NB) ? ghist[t] : 0;
    lds[t] = own;
    __syncthreads();
    for (int off = 1; off < 512; off <<= 1) {
        int v = (t >= off) ? lds[t - off] : 0;
        __syncthreads();
        lds[t] += v;
        __syncthreads();
    }
    int excl = lds[t] - own;
    bstart[t] = excl;
    if (t == 511) bstart[512] = lds[511];
    if (t < NB) gcursor[t] = excl;
}

// block-privatized bin scatter: {src | dstl<<20, w} into bucket-contiguous ebuf
__global__ __launch_bounds__(256) void fillA_kernel(const void* __restrict__ ei,
                                                    const int* __restrict__ flag,
                                                    const float* __restrict__ ew,
                                                    int* __restrict__ gcursor,
                                                    int2* __restrict__ ebuf) {
    __shared__ int cnt[512];
    __shared__ int base[512];
    int t = threadIdx.x;
    cnt[t] = 0;
    cnt[t + 256] = 0;
    __syncthreads();
    int f = *flag;
    int eb = blockIdx.x * 256 * FILL_EPT;
    int src[FILL_EPT], bin[FILL_EPT], rank[FILL_EPT];
    float w[FILL_EPT];
#pragma unroll
    for (int k = 0; k < FILL_EPT; ++k) {
        int e = eb + k * 256 + t;
        bin[k] = -1;
        if (e < N_EDGES) {
            int s = load_idx(ei, f, (size_t)e);
            int d = load_idx(ei, f, (size_t)N_EDGES + e);
            int b = d / NPB;
            src[k] = s | ((d - b * NPB) << 20);
            w[k] = ew[e];
            bin[k] = b;
            rank[k] = atomicAdd(&cnt[b], 1);
        }
    }
    __syncthreads();
    if (cnt[t] > 0) base[t] = atomicAdd(&gcursor[t], cnt[t]);
    if (cnt[t + 256] > 0) base[t + 256] = atomicAdd(&gcursor[t + 256], cnt[t + 256]);
    __syncthreads();
#pragma unroll
    for (int k = 0; k < FILL_EPT; ++k) {
        if (bin[k] >= 0) {
            int pos = base[bin[k]] + rank[k];
            ebuf[pos] = make_int2(src[k], __float_as_int(w[k]));
        }
    }
}

// per-bucket counting sort -> exact CSR (ebuf2) + row_ptr
__global__ __launch_bounds__(256) void sortB_kernel(const int2* __restrict__ ebuf,
                                                    const int* __restrict__ bstart,
                                                    int2* __restrict__ ebuf2,
                                                    int* __restrict__ row_ptr) {
    __shared__ int cnt[NPB];
    __shared__ int sc[256];
    __shared__ int cur[NPB];
    int t = threadIdx.x, b = blockIdx.x;
    for (int i = t; i < NPB; i += 256) cnt[i] = 0;
    __syncthreads();
    int start = bstart[b], end = bstart[b + 1];
    for (int i = start + t; i < end; i += 256) {
        int dl = ((u32)ebuf[i].x) >> 20;
        atomicAdd(&cnt[dl], 1);
    }
    __syncthreads();
    int own = (t < NPB) ? cnt[t] : 0;
    sc[t] = own;
    __syncthreads();
    for (int off = 1; off < 256; off <<= 1) {
        int v = (t >= off) ? sc[t - off] : 0;
        __syncthreads();
        sc[t] += v;
        __syncthreads();
    }
    int excl = sc[t] - own;
    if (t < NPB) {
        cur[t] = excl;
        int node = b * NPB + t;
        if (node < N_NODES) row_ptr[node] = start + excl;
    }
    if (b == 0 && t == 0) row_ptr[N_NODES] = N_EDGES;
    __syncthreads();
    for (int i = start + t; i < end; i += 256) {
        int2 p = ebuf[i];
        int dl = ((u32)p.x) >> 20;
        int pos = start + atomicAdd(&cur[dl], 1);
        ebuf2[pos] = make_int2(p.x & 0xFFFFF, p.y);
    }
}

// ---------- gemm1: LDS-tiled 128x64x128, 512 threads, 8 waves share Wsh ----------
// LDS 49.6 KB -> 3 blocks/CU; __launch_bounds__(512,6) caps VGPR at ~85 (uses 84)
__global__ __launch_bounds__(512, 6) void gemm1_kernel(const float* __restrict__ X,
                                                       const float* __restrict__ W,
                                                       u32* __restrict__ Y) {
    __shared__ float Wsh[NFEAT * NHID];  // 32 KB
    __shared__ float Xs[GR][33];         // 16.9 KB (pad 33 breaks bank stride)
    int t = threadIdx.x;
    int rb = blockIdx.x * GR;
    for (int i = t; i < NFEAT * NHID; i += 512) Wsh[i] = W[i];
    float acc[4][4];
#pragma unroll
    for (int i = 0; i < 4; ++i)
#pragma unroll
        for (int j = 0; j < 4; ++j) acc[i][j] = 0.f;
    int r0 = (t >> 4) * 4;  // 32 row-groups * 4 rows = 128
    int c0 = (t & 15) * 4;  // 16 col-groups * 4 cols = 64
    for (int kk = 0; kk < NFEAT; kk += 32) {
        __syncthreads();  // protects Xs reuse; first iter also covers Wsh staging
        for (int idx = t; idx < GR * 32; idx += 512) {
            int r = idx >> 5, c = idx & 31;
            int row = rb + r;
            Xs[r][c] = (row < N_NODES) ? X[(size_t)row * NFEAT + kk + c] : 0.f;
        }
        __syncthreads();
#pragma unroll
        for (int k = 0; k < 32; ++k) {
            float x0 = Xs[r0 + 0][k];
            float x1 = Xs[r0 + 1][k];
            float x2 = Xs[r0 + 2][k];
            float x3 = Xs[r0 + 3][k];
            const float* wr = &Wsh[(kk + k) * NHID + c0];
            float w0 = wr[0], w1 = wr[1], w2 = wr[2], w3 = wr[3];
            acc[0][0] += x0 * w0; acc[0][1] += x0 * w1; acc[0][2] += x0 * w2; acc[0][3] += x0 * w3;
            acc[1][0] += x1 * w0; acc[1][1] += x1 * w1; acc[1][2] += x1 * w2; acc[1][3] += x1 * w3;
            acc[2][0] += x2 * w0; acc[2][1] += x2 * w1; acc[2][2] += x2 * w2; acc[2][3] += x2 * w3;
            acc[3][0] += x3 * w0; acc[3][1] += x3 * w1; acc[3][2] += x3 * w2; acc[3][3] += x3 * w3;
        }
    }
#pragma unroll
    for (int i = 0; i < 4; ++i) {
        int row = rb + r0 + i;
        if (row < N_NODES) {
            uint2 o;
            o.x = pack_bf16(acc[i][0], acc[i][1]);
            o.y = pack_bf16(acc[i][2], acc[i][3]);
            *(uint2*)(Y + (size_t)row * (NHID / 2) + (c0 >> 1)) = o;
        }
    }
}

// gemm2: h[N,64] fp32 @ W2[64,16] -> hwb packed bf16 [N, 8 u32]
__global__ __launch_bounds__(256) void gemm2_kernel(const float* __restrict__ H,
                                                    const float* __restrict__ W,
                                                    u32* __restrict__ Y) {
    __shared__ float Ws[NHID * NCLASS];  // 4 KB
    for (int i = threadIdx.x; i < NHID * NCLASS; i += 256) Ws[i] = W[i];
    __syncthreads();
    int row = blockIdx.x * 256 + threadIdx.x;
    if (row >= N_NODES) return;
    float acc[NCLASS];
#pragma unroll
    for (int j = 0; j < NCLASS; ++j) acc[j] = 0.f;
    const float* hr = H + (size_t)row * NHID;
    for (int k = 0; k < NHID; k += 4) {
        float4 hv = *(const float4*)(hr + k);
#pragma unroll
        for (int j = 0; j < NCLASS; ++j) {
            acc[j] += hv.x * Ws[(k + 0) * NCLASS + j];
            acc[j] += hv.y * Ws[(k + 1) * NCLASS + j];
            acc[j] += hv.z * Ws[(k + 2) * NCLASS + j];
            acc[j] += hv.w * Ws[(k + 3) * NCLASS + j];
        }
    }
    u32* yr = Y + (size_t)row * (NCLASS / 2);
    uint4 o0, o1;
    o0.x = pack_bf16(acc[0], acc[1]);
    o0.y = pack_bf16(acc[2], acc[3]);
    o0.z = pack_bf16(acc[4], acc[5]);
    o0.w = pack_bf16(acc[6], acc[7]);
    o1.x = pack_bf16(acc[8], acc[9]);
    o1.y = pack_bf16(acc[10], acc[11]);
    o1.z = pack_bf16(acc[12], acc[13]);
    o1.w = pack_bf16(acc[14], acc[15]);
    *(uint4*)(yr + 0) = o0;
    *(uint4*)(yr + 4) = o1;
}

// ---------- CSR aggregation (edge-parallel waves, no atomics) ----------
// Layer 1: half-wave per node, lane owns 2 packed feats; masked 4-wide loop
// (clamped index + zeroed weight) keeps 4 gathers in flight on every iter.
__global__ __launch_bounds__(256) void agg1_kernel(const u32* __restrict__ xwb,
                                                   const int* __restrict__ row_ptr,
                                                   const int2* __restrict__ ep,
                                                   float* __restrict__ h) {
    int t = blockIdx.x * 256 + threadIdx.x;
    int node = t >> 5;
    int ln = t & 31;
    if (node >= N_NODES) return;
    int start = row_ptr[node], end = row_ptr[node + 1];
    float a0x = 0.f, a0y = 0.f, a1x = 0.f, a1y = 0.f;
    float a2x = 0.f, a2y = 0.f, a3x = 0.f, a3y = 0.f;
    int last = end - 1;
    for (int i = start; i < end; i += 4) {
        int i1 = min(i + 1, last), i2 = min(i + 2, last), i3 = min(i + 3, last);
        int2 p0 = ep[i];
        int2 p1 = ep[i1];
        int2 p2 = ep[i2];
        int2 p3 = ep[i3];
        u32 u0 = xwb[(size_t)p0.x * 32 + ln];
        u32 u1 = xwb[(size_t)p1.x * 32 + ln];
        u32 u2 = xwb[(size_t)p2.x * 32 + ln];
        u32 u3 = xwb[(size_t)p3.x * 32 + ln];
        float w0 = __int_as_float(p0.y);
        float w1 = (i + 1 < end) ? __int_as_float(p1.y) : 0.f;
        float w2 = (i + 2 < end) ? __int_as_float(p2.y) : 0.f;
        float w3 = (i + 3 < end) ? __int_as_float(p3.y) : 0.f;
        a0x += w0 * bf16_lo(u0); a0y += w0 * bf16_hi(u0);
        a1x += w1 * bf16_lo(u1); a1y += w1 * bf16_hi(u1);
        a2x += w2 * bf16_lo(u2); a2y += w2 * bf16_hi(u2);
        a3x += w3 * bf16_lo(u3); a3y += w3 * bf16_hi(u3);
    }
    float sx = (a0x + a1x) + (a2x + a3x);
    float sy = (a0y + a1y) + (a2y + a3y);
    *(float2*)(h + (size_t)node * NHID + 2 * ln) =
        make_float2(fmaxf(sx, 0.f), fmaxf(sy, 0.f));
}

// Layer 2: one wave per node; lane = sub*8 + p, 8 edges in flight, shfl reduce.
__global__ __launch_bounds__(256) void agg2_kernel(const u32* __restrict__ hwb,
                                                   const int* __restrict__ row_ptr,
                                                   const int2* __restrict__ ep,
                                                   float* __restrict__ out) {
    int t = blockIdx.x * 256 + threadIdx.x;
    int node = t >> 6;
    int lane = t & 63;
    int p = lane & 7;
    int sub = lane >> 3;
    if (node >= N_NODES) return;
    int start = row_ptr[node], end = row_ptr[node + 1];
    float ax = 0.f, ay = 0.f;
    for (int i = start + sub; i < end; i += 8) {
        int2 pr = ep[i];
        u32 u = hwb[(size_t)pr.x * 8 + p];
        float w = __int_as_float(pr.y);
        ax += w * bf16_lo(u);
        ay += w * bf16_hi(u);
    }
    ax += __shfl_xor(ax, 8, 64);  ay += __shfl_xor(ay, 8, 64);
    ax += __shfl_xor(ax, 16, 64); ay += __shfl_xor(ay, 16, 64);
    ax += __shfl_xor(ax, 32, 64); ay += __shfl_xor(ay, 32, 64);
    if (sub == 0) *(float2*)(out + (size_t)node * NCLASS + 2 * p) = make_float2(ax, ay);
}

extern "C" void kernel_launch(void* const* d_in, const int* in_sizes, int n_in,
                              void* d_out, int out_size, void* d_ws, size_t ws_size,
                              hipStream_t stream) {
    const float* x  = (const float*)d_in[0];
    const void*  ei = d_in[1];
    const float* ew = (const float*)d_in[2];
    const float* W1 = (const float*)d_in[3];
    const float* W2 = (const float*)d_in[4];
    float* out = (float*)d_out;

    char* ws = (char*)d_ws;
    size_t off = 0;
    auto take = [&](size_t bytes) {
        char* p = ws + off;
        off += (bytes + 511) & ~(size_t)511;
        return p;
    };
    int*   flag    = (int*)take(4);
    int*   ghist   = (int*)take(512 * 4);
    int*   bstart  = (int*)take(513 * 4);
    int*   gcursor = (int*)take(512 * 4);
    int*   row_ptr = (int*)take((size_t)(N_NODES + 1) * 4);
    int2*  ebuf    = (int2*)take((size_t)N_EDGES * 8);
    int2*  ebuf2   = (int2*)take((size_t)N_EDGES * 8);
    u32*   xwb     = (u32*)take((size_t)N_NODES * (NHID / 2) * 4);  // bf16 packed
    float* h       = (float*)take((size_t)N_NODES * NHID * 4);
    u32*   hwb     = xwb;  // reuse: xwb dead after agg1

    detect_kernel<<<1, 256, 0, stream>>>((const u32*)ei, flag);
    hipMemsetAsync(ghist, 0, 512 * 4, stream);
    histA_kernel<<<HIST_BLOCKS, 256, 0, stream>>>(ei, flag, ghist);
    scanA_kernel<<<1, 512, 0, stream>>>(ghist, bstart, gcursor);
    fillA_kernel<<<FILL_BLOCKS, 256, 0, stream>>>(ei, flag, ew, gcursor, ebuf);
    sortB_kernel<<<NB, 256, 0, stream>>>(ebuf, bstart, ebuf2, row_ptr);

    gemm1_kernel<<<(N_NODES + GR - 1) / GR, 512, 0, stream>>>(x, W1, xwb);
    agg1_kernel<<<(N_NODES * 32 + 255) / 256, 256, 0, stream>>>(xwb, row_ptr, ebuf2, h);
    gemm2_kernel<<<(N_NODES + 255) / 256, 256, 0, stream>>>(h, W2, hwb);
    agg2_kernel<<<(N_NODES * 64 + 255) / 256, 256, 0, stream>>>(hwb, row_ptr, ebuf2, out);
}

// Round 7
// 172.678 us; speedup vs baseline: 4.5894x; 1.2005x over previous
//
#include <hip/hip_runtime.h>

#define N_NODES 100000
#define N_EDGES 1600000
#define NFEAT 128
#define NHID 64
#define NCLASS 16

#define NPB 196                    // dst-nodes per bucket
#define NB 511                     // ceil(N_NODES / NPB)
#define HIST_EPT 16
#define HIST_BLOCKS ((N_EDGES + 256 * HIST_EPT - 1) / (256 * HIST_EPT))  // 391
#define FILL_EPT 8
#define FILL_BLOCKS ((N_EDGES + 256 * FILL_EPT - 1) / (256 * FILL_EPT))  // 782
#define NTILES ((N_NODES + 15) / 16)            // 6250 (exact: 100000 = 6250*16)
#define GEMM_BLOCKS ((NTILES + 3) / 4)          // 1563

typedef unsigned int u32;
typedef __attribute__((ext_vector_type(8))) short bf16x8;   // 8 bf16 in 4 VGPRs
typedef __attribute__((ext_vector_type(4))) float f32x4;

__device__ __forceinline__ u32 pack_bf16(float a, float b) {
    u32 ua = __float_as_uint(a);
    u32 ub = __float_as_uint(b);
    ua = (ua + 0x7fffu + ((ua >> 16) & 1u)) >> 16;
    ub = (ub + 0x7fffu + ((ub >> 16) & 1u)) >> 16;
    return ua | (ub << 16);
}
__device__ __forceinline__ short f2bf(float f) {
    u32 u = __float_as_uint(f);
    u = (u + 0x7fffu + ((u >> 16) & 1u)) >> 16;
    return (short)u;
}
__device__ __forceinline__ float bf16_lo(u32 u) { return __uint_as_float(u << 16); }
__device__ __forceinline__ float bf16_hi(u32 u) { return __uint_as_float(u & 0xffff0000u); }

// ---------- edge-index dtype detection (int64 ref vs int32 harness) ----------
__global__ void detect_kernel(const u32* __restrict__ ei, int* __restrict__ flag) {
    __shared__ int any_nz;
    if (threadIdx.x == 0) any_nz = 0;
    __syncthreads();
    u32 v = ei[2 * threadIdx.x + 1];
    if (v != 0) any_nz = 1;
    __syncthreads();
    if (threadIdx.x == 0) *flag = any_nz;  // 1 => int32 data, 0 => int64 data
}

__device__ __forceinline__ int load_idx(const void* ei, int flag, size_t pos) {
    return flag ? ((const int*)ei)[pos] : (int)((const long long*)ei)[pos];
}

// ---------- coarse binning: LDS-privatized histogram over NB buckets ----------
__global__ __launch_bounds__(256) void histA_kernel(const void* __restrict__ ei,
                                                    const int* __restrict__ flag,
                                                    int* __restrict__ ghist) {
    __shared__ int cnt[512];
    int t = threadIdx.x;
    cnt[t] = 0;
    cnt[t + 256] = 0;
    __syncthreads();
    int f = *flag;
    int base = blockIdx.x * 256 * HIST_EPT;
#pragma unroll
    for (int k = 0; k < HIST_EPT; ++k) {
        int e = base + k * 256 + t;
        if (e < N_EDGES) {
            int d = load_idx(ei, f, (size_t)N_EDGES + e);
            atomicAdd(&cnt[d / NPB], 1);
        }
    }
    __syncthreads();
    if (cnt[t] > 0) atomicAdd(&ghist[t], cnt[t]);
    if (cnt[t + 256] > 0) atomicAdd(&ghist[t + 256], cnt[t + 256]);
}

// single-block scan of NB bucket counts -> bstart (exclusive) + gcursor
__global__ __launch_bounds__(512) void scanA_kernel(const int* __restrict__ ghist,
                                                    int* __restrict__ bstart,
                                                    int* __restrict__ gcursor) {
    __shared__ int lds[512];
    int t = threadIdx.x;
    int own = (t < NB) ? ghist[t] : 0;
    lds[t] = own;
    __syncthreads();
    for (int off = 1; off < 512; off <<= 1) {
        int v = (t >= off) ? lds[t - off] : 0;
        __syncthreads();
        lds[t] += v;
        __syncthreads();
    }
    int excl = lds[t] - own;
    bstart[t] = excl;
    if (t == 511) bstart[512] = lds[511];
    if (t < NB) gcursor[t] = excl;
}

// block-privatized bin scatter: {src | dstl<<20, w} into bucket-contiguous ebuf
__global__ __launch_bounds__(256) void fillA_kernel(const void* __restrict__ ei,
                                                    const int* __restrict__ flag,
                                                    const float* __restrict__ ew,
                                                    int* __restrict__ gcursor,
                                                    int2* __restrict__ ebuf) {
    __shared__ int cnt[512];
    __shared__ int base[512];
    int t = threadIdx.x;
    cnt[t] = 0;
    cnt[t + 256] = 0;
    __syncthreads();
    int f = *flag;
    int eb = blockIdx.x * 256 * FILL_EPT;
    int src[FILL_EPT], bin[FILL_EPT], rank[FILL_EPT];
    float w[FILL_EPT];
#pragma unroll
    for (int k = 0; k < FILL_EPT; ++k) {
        int e = eb + k * 256 + t;
        bin[k] = -1;
        if (e < N_EDGES) {
            int s = load_idx(ei, f, (size_t)e);
            int d = load_idx(ei, f, (size_t)N_EDGES + e);
            int b = d / NPB;
            src[k] = s | ((d - b * NPB) << 20);
            w[k] = ew[e];
            bin[k] = b;
            rank[k] = atomicAdd(&cnt[b], 1);
        }
    }
    __syncthreads();
    if (cnt[t] > 0) base[t] = atomicAdd(&gcursor[t], cnt[t]);
    if (cnt[t + 256] > 0) base[t + 256] = atomicAdd(&gcursor[t + 256], cnt[t + 256]);
    __syncthreads();
#pragma unroll
    for (int k = 0; k < FILL_EPT; ++k) {
        if (bin[k] >= 0) {
            int pos = base[bin[k]] + rank[k];
            ebuf[pos] = make_int2(src[k], __float_as_int(w[k]));
        }
    }
}

// per-bucket counting sort -> exact CSR (ebuf2) + row_ptr
__global__ __launch_bounds__(256) void sortB_kernel(const int2* __restrict__ ebuf,
                                                    const int* __restrict__ bstart,
                                                    int2* __restrict__ ebuf2,
                                                    int* __restrict__ row_ptr) {
    __shared__ int cnt[NPB];
    __shared__ int sc[256];
    __shared__ int cur[NPB];
    int t = threadIdx.x, b = blockIdx.x;
    for (int i = t; i < NPB; i += 256) cnt[i] = 0;
    __syncthreads();
    int start = bstart[b], end = bstart[b + 1];
    for (int i = start + t; i < end; i += 256) {
        int dl = ((u32)ebuf[i].x) >> 20;
        atomicAdd(&cnt[dl], 1);
    }
    __syncthreads();
    int own = (t < NPB) ? cnt[t] : 0;
    sc[t] = own;
    __syncthreads();
    for (int off = 1; off < 256; off <<= 1) {
        int v = (t >= off) ? sc[t - off] : 0;
        __syncthreads();
        sc[t] += v;
        __syncthreads();
    }
    int excl = sc[t] - own;
    if (t < NPB) {
        cur[t] = excl;
        int node = b * NPB + t;
        if (node < N_NODES) row_ptr[node] = start + excl;
    }
    if (b == 0 && t == 0) row_ptr[N_NODES] = N_EDGES;
    __syncthreads();
    for (int i = start + t; i < end; i += 256) {
        int2 p = ebuf[i];
        int dl = ((u32)p.x) >> 20;
        int pos = start + atomicAdd(&cur[dl], 1);
        ebuf2[pos] = make_int2(p.x & 0xFFFFF, p.y);
    }
}

// ---------- gemm1 via MFMA: D = W1^T (A) x x^T (B), 16 nodes per wave ----------
// A[n][k] = W1[k][n]; lane(g=l>>4, r=l&15): A row n=r, k=g*8+j  (j=0..7)
// B[k][m] = x[m][k]; lane: B col m=r (node), k=g*8+j -> 32B contiguous row read
// D[n][m]: lane holds node m=r, feats n = nt*16 + g*4 + {0..3} (consecutive!)
__global__ __launch_bounds__(256) void gemm1_kernel(const float* __restrict__ X,
                                                    const float* __restrict__ W,
                                                    u32* __restrict__ Y) {
    __shared__ float Wsh[NFEAT * NHID];  // 32 KB
    int t = threadIdx.x;
    for (int i = t; i < NFEAT * NHID; i += 256) Wsh[i] = W[i];
    __syncthreads();
    int wid = t >> 6;
    int lane = t & 63;
    int r = lane & 15, g = lane >> 4;
    int m0 = (blockIdx.x * 4 + wid) * 16;
    if (m0 >= N_NODES) return;

    bf16x8 af[4][4];  // [ntile][ktile]
#pragma unroll
    for (int nt = 0; nt < 4; ++nt)
#pragma unroll
        for (int kt = 0; kt < 4; ++kt)
#pragma unroll
            for (int j = 0; j < 8; ++j)
                af[nt][kt][j] = f2bf(Wsh[(kt * 32 + g * 8 + j) * NHID + nt * 16 + r]);

    const float* xr = X + (size_t)(m0 + r) * NFEAT + g * 8;
    bf16x8 bfr[4];
#pragma unroll
    for (int kt = 0; kt < 4; ++kt) {
        float4 v0 = *(const float4*)(xr + kt * 32);
        float4 v1 = *(const float4*)(xr + kt * 32 + 4);
        bfr[kt][0] = f2bf(v0.x); bfr[kt][1] = f2bf(v0.y);
        bfr[kt][2] = f2bf(v0.z); bfr[kt][3] = f2bf(v0.w);
        bfr[kt][4] = f2bf(v1.x); bfr[kt][5] = f2bf(v1.y);
        bfr[kt][6] = f2bf(v1.z); bfr[kt][7] = f2bf(v1.w);
    }

    u32* yr = Y + (size_t)(m0 + r) * (NHID / 2);
#pragma unroll
    for (int nt = 0; nt < 4; ++nt) {
        f32x4 acc = {0.f, 0.f, 0.f, 0.f};
#pragma unroll
        for (int kt = 0; kt < 4; ++kt)
            acc = __builtin_amdgcn_mfma_f32_16x16x32_bf16(af[nt][kt], bfr[kt], acc, 0, 0, 0);
        uint2 o;
        o.x = pack_bf16(acc[0], acc[1]);
        o.y = pack_bf16(acc[2], acc[3]);
        *(uint2*)(yr + nt * 8 + g * 2) = o;
    }
}

// ---------- gemm2 via MFMA: D = W2^T x h^T, 16 nodes per wave, K=64 ----------
__global__ __launch_bounds__(256) void gemm2_kernel(const float* __restrict__ H,
                                                    const float* __restrict__ W,
                                                    u32* __restrict__ Y) {
    __shared__ float Wsh[NHID * NCLASS];  // 4 KB
    int t = threadIdx.x;
    for (int i = t; i < NHID * NCLASS; i += 256) Wsh[i] = W[i];
    __syncthreads();
    int wid = t >> 6;
    int lane = t & 63;
    int r = lane & 15, g = lane >> 4;
    int m0 = (blockIdx.x * 4 + wid) * 16;
    if (m0 >= N_NODES) return;

    bf16x8 af[2];
#pragma unroll
    for (int kt = 0; kt < 2; ++kt)
#pragma unroll
        for (int j = 0; j < 8; ++j)
            af[kt][j] = f2bf(Wsh[(kt * 32 + g * 8 + j) * NCLASS + r]);

    const float* hr = H + (size_t)(m0 + r) * NHID + g * 8;
    bf16x8 bfr[2];
#pragma unroll
    for (int kt = 0; kt < 2; ++kt) {
        float4 v0 = *(const float4*)(hr + kt * 32);
        float4 v1 = *(const float4*)(hr + kt * 32 + 4);
        bfr[kt][0] = f2bf(v0.x); bfr[kt][1] = f2bf(v0.y);
        bfr[kt][2] = f2bf(v0.z); bfr[kt][3] = f2bf(v0.w);
        bfr[kt][4] = f2bf(v1.x); bfr[kt][5] = f2bf(v1.y);
        bfr[kt][6] = f2bf(v1.z); bfr[kt][7] = f2bf(v1.w);
    }

    f32x4 acc = {0.f, 0.f, 0.f, 0.f};
    acc = __builtin_amdgcn_mfma_f32_16x16x32_bf16(af[0], bfr[0], acc, 0, 0, 0);
    acc = __builtin_amdgcn_mfma_f32_16x16x32_bf16(af[1], bfr[1], acc, 0, 0, 0);

    u32* yr = Y + (size_t)(m0 + r) * (NCLASS / 2);
    uint2 o;
    o.x = pack_bf16(acc[0], acc[1]);
    o.y = pack_bf16(acc[2], acc[3]);
    *(uint2*)(yr + g * 2) = o;
}

// ---------- CSR aggregation (edge-parallel waves, no atomics) ----------
// Layer 1: half-wave per node, lane owns 2 packed feats; masked 4-wide loop.
__global__ __launch_bounds__(256) void agg1_kernel(const u32* __restrict__ xwb,
                                                   const int* __restrict__ row_ptr,
                                                   const int2* __restrict__ ep,
                                                   float* __restrict__ h) {
    int t = blockIdx.x * 256 + threadIdx.x;
    int node = t >> 5;
    int ln = t & 31;
    if (node >= N_NODES) return;
    int start = row_ptr[node], end = row_ptr[node + 1];
    float a0x = 0.f, a0y = 0.f, a1x = 0.f, a1y = 0.f;
    float a2x = 0.f, a2y = 0.f, a3x = 0.f, a3y = 0.f;
    int last = end - 1;
    for (int i = start; i < end; i += 4) {
        int i1 = min(i + 1, last), i2 = min(i + 2, last), i3 = min(i + 3, last);
        int2 p0 = ep[i];
        int2 p1 = ep[i1];
        int2 p2 = ep[i2];
        int2 p3 = ep[i3];
        u32 u0 = xwb[(size_t)p0.x * 32 + ln];
        u32 u1 = xwb[(size_t)p1.x * 32 + ln];
        u32 u2 = xwb[(size_t)p2.x * 32 + ln];
        u32 u3 = xwb[(size_t)p3.x * 32 + ln];
        float w0 = __int_as_float(p0.y);
        float w1 = (i + 1 < end) ? __int_as_float(p1.y) : 0.f;
        float w2 = (i + 2 < end) ? __int_as_float(p2.y) : 0.f;
        float w3 = (i + 3 < end) ? __int_as_float(p3.y) : 0.f;
        a0x += w0 * bf16_lo(u0); a0y += w0 * bf16_hi(u0);
        a1x += w1 * bf16_lo(u1); a1y += w1 * bf16_hi(u1);
        a2x += w2 * bf16_lo(u2); a2y += w2 * bf16_hi(u2);
        a3x += w3 * bf16_lo(u3); a3y += w3 * bf16_hi(u3);
    }
    float sx = (a0x + a1x) + (a2x + a3x);
    float sy = (a0y + a1y) + (a2y + a3y);
    *(float2*)(h + (size_t)node * NHID + 2 * ln) =
        make_float2(fmaxf(sx, 0.f), fmaxf(sy, 0.f));
}

// Layer 2: one wave per node; lane = sub*8 + p, 8 edges in flight, shfl reduce.
__global__ __launch_bounds__(256) void agg2_kernel(const u32* __restrict__ hwb,
                                                   const int* __restrict__ row_ptr,
                                                   const int2* __restrict__ ep,
                                                   float* __restrict__ out) {
    int t = blockIdx.x * 256 + threadIdx.x;
    int node = t >> 6;
    int lane = t & 63;
    int p = lane & 7;
    int sub = lane >> 3;
    if (node >= N_NODES) return;
    int start = row_ptr[node], end = row_ptr[node + 1];
    float ax = 0.f, ay = 0.f;
    for (int i = start + sub; i < end; i += 8) {
        int2 pr = ep[i];
        u32 u = hwb[(size_t)pr.x * 8 + p];
        float w = __int_as_float(pr.y);
        ax += w * bf16_lo(u);
        ay += w * bf16_hi(u);
    }
    ax += __shfl_xor(ax, 8, 64);  ay += __shfl_xor(ay, 8, 64);
    ax += __shfl_xor(ax, 16, 64); ay += __shfl_xor(ay, 16, 64);
    ax += __shfl_xor(ax, 32, 64); ay += __shfl_xor(ay, 32, 64);
    if (sub == 0) *(float2*)(out + (size_t)node * NCLASS + 2 * p) = make_float2(ax, ay);
}

extern "C" void kernel_launch(void* const* d_in, const int* in_sizes, int n_in,
                              void* d_out, int out_size, void* d_ws, size_t ws_size,
                              hipStream_t stream) {
    const float* x  = (const float*)d_in[0];
    const void*  ei = d_in[1];
    const float* ew = (const float*)d_in[2];
    const float* W1 = (const float*)d_in[3];
    const float* W2 = (const float*)d_in[4];
    float* out = (float*)d_out;

    char* ws = (char*)d_ws;
    size_t off = 0;
    auto take = [&](size_t bytes) {
        char* p = ws + off;
        off += (bytes + 511) & ~(size_t)511;
        return p;
    };
    int*   flag    = (int*)take(4);
    int*   ghist   = (int*)take(512 * 4);
    int*   bstart  = (int*)take(513 * 4);
    int*   gcursor = (int*)take(512 * 4);
    int*   row_ptr = (int*)take((size_t)(N_NODES + 1) * 4);
    int2*  ebuf    = (int2*)take((size_t)N_EDGES * 8);
    int2*  ebuf2   = (int2*)take((size_t)N_EDGES * 8);
    u32*   xwb     = (u32*)take((size_t)N_NODES * (NHID / 2) * 4);  // bf16 packed
    float* h       = (float*)take((size_t)N_NODES * NHID * 4);
    u32*   hwb     = xwb;  // reuse: xwb dead after agg1

    detect_kernel<<<1, 256, 0, stream>>>((const u32*)ei, flag);
    hipMemsetAsync(ghist, 0, 512 * 4, stream);
    histA_kernel<<<HIST_BLOCKS, 256, 0, stream>>>(ei, flag, ghist);
    scanA_kernel<<<1, 512, 0, stream>>>(ghist, bstart, gcursor);
    fillA_kernel<<<FILL_BLOCKS, 256, 0, stream>>>(ei, flag, ew, gcursor, ebuf);
    sortB_kernel<<<NB, 256, 0, stream>>>(ebuf, bstart, ebuf2, row_ptr);

    gemm1_kernel<<<GEMM_BLOCKS, 256, 0, stream>>>(x, W1, xwb);
    agg1_kernel<<<(N_NODES * 32 + 255) / 256, 256, 0, stream>>>(xwb, row_ptr, ebuf2, h);
    gemm2_kernel<<<GEMM_BLOCKS, 256, 0, stream>>>(h, W2, hwb);
    agg2_kernel<<<(N_NODES * 64 + 255) / 256, 256, 0, stream>>>(hwb, row_ptr, ebuf2, out);
}

// Round 8
// 168.672 us; speedup vs baseline: 4.6984x; 1.0237x over previous
//
#include <hip/hip_runtime.h>

#define N_NODES 100000
#define N_EDGES 1600000
#define NFEAT 128
#define NHID 64
#define NCLASS 16

#define NPB 196                    // dst-nodes per bucket
#define NB 511                     // ceil(N_NODES / NPB)
#define HIST_EPT 16
#define HIST_BLOCKS ((N_EDGES + 256 * HIST_EPT - 1) / (256 * HIST_EPT))  // 391
#define FILL_EPT 8
#define FILL_BLOCKS ((N_EDGES + 256 * FILL_EPT - 1) / (256 * FILL_EPT))  // 782
#define NTILES ((N_NODES + 15) / 16)            // 6250
#define GEMM_BLOCKS ((NTILES + 3) / 4)          // 1563

typedef unsigned int u32;
typedef __attribute__((ext_vector_type(8))) short bf16x8;
typedef __attribute__((ext_vector_type(4))) float f32x4;

__device__ __forceinline__ u32 pack_bf16(float a, float b) {
    u32 ua = __float_as_uint(a);
    u32 ub = __float_as_uint(b);
    ua = (ua + 0x7fffu + ((ua >> 16) & 1u)) >> 16;
    ub = (ub + 0x7fffu + ((ub >> 16) & 1u)) >> 16;
    return ua | (ub << 16);
}
__device__ __forceinline__ short f2bf(float f) {
    u32 u = __float_as_uint(f);
    u = (u + 0x7fffu + ((u >> 16) & 1u)) >> 16;
    return (short)u;
}
__device__ __forceinline__ float bf16_lo(u32 u) { return __uint_as_float(u << 16); }
__device__ __forceinline__ float bf16_hi(u32 u) { return __uint_as_float(u & 0xffff0000u); }

// ---------- edge-index dtype detection (int64 ref vs int32 harness) ----------
__global__ void detect_kernel(const u32* __restrict__ ei, int* __restrict__ flag) {
    __shared__ int any_nz;
    if (threadIdx.x == 0) any_nz = 0;
    __syncthreads();
    u32 v = ei[2 * threadIdx.x + 1];
    if (v != 0) any_nz = 1;
    __syncthreads();
    if (threadIdx.x == 0) *flag = any_nz;  // 1 => int32 data, 0 => int64 data
}

__device__ __forceinline__ int load_idx(const void* ei, int flag, size_t pos) {
    return flag ? ((const int*)ei)[pos] : (int)((const long long*)ei)[pos];
}

// ---------- coarse binning: LDS-privatized histogram over NB buckets ----------
__global__ __launch_bounds__(256) void histA_kernel(const void* __restrict__ ei,
                                                    const int* __restrict__ flag,
                                                    int* __restrict__ ghist) {
    __shared__ int cnt[512];
    int t = threadIdx.x;
    cnt[t] = 0;
    cnt[t + 256] = 0;
    __syncthreads();
    int f = *flag;
    int base = blockIdx.x * 256 * HIST_EPT;
#pragma unroll
    for (int k = 0; k < HIST_EPT; ++k) {
        int e = base + k * 256 + t;
        if (e < N_EDGES) {
            int d = load_idx(ei, f, (size_t)N_EDGES + e);
            atomicAdd(&cnt[d / NPB], 1);
        }
    }
    __syncthreads();
    if (cnt[t] > 0) atomicAdd(&ghist[t], cnt[t]);
    if (cnt[t + 256] > 0) atomicAdd(&ghist[t + 256], cnt[t + 256]);
}

// single-block scan of NB bucket counts -> bstart (exclusive) + gcursor
__global__ __launch_bounds__(512) void scanA_kernel(const int* __restrict__ ghist,
                                                    int* __restrict__ bstart,
                                                    int* __restrict__ gcursor) {
    __shared__ int lds[512];
    int t = threadIdx.x;
    int own = (t < NB) ? ghist[t] : 0;
    lds[t] = own;
    __syncthreads();
    for (int off = 1; off < 512; off <<= 1) {
        int v = (t >= off) ? lds[t - off] : 0;
        __syncthreads();
        lds[t] += v;
        __syncthreads();
    }
    int excl = lds[t] - own;
    bstart[t] = excl;
    if (t == 511) bstart[512] = lds[511];
    if (t < NB) gcursor[t] = excl;
}

// block-privatized bin scatter: {src | dstl<<20, w} into bucket-contiguous ebuf
__global__ __launch_bounds__(256) void fillA_kernel(const void* __restrict__ ei,
                                                    const int* __restrict__ flag,
                                                    const float* __restrict__ ew,
                                                    int* __restrict__ gcursor,
                                                    int2* __restrict__ ebuf) {
    __shared__ int cnt[512];
    __shared__ int base[512];
    int t = threadIdx.x;
    cnt[t] = 0;
    cnt[t + 256] = 0;
    __syncthreads();
    int f = *flag;
    int eb = blockIdx.x * 256 * FILL_EPT;
    int src[FILL_EPT], bin[FILL_EPT], rank[FILL_EPT];
    float w[FILL_EPT];
#pragma unroll
    for (int k = 0; k < FILL_EPT; ++k) {
        int e = eb + k * 256 + t;
        bin[k] = -1;
        if (e < N_EDGES) {
            int s = load_idx(ei, f, (size_t)e);
            int d = load_idx(ei, f, (size_t)N_EDGES + e);
            int b = d / NPB;
            src[k] = s | ((d - b * NPB) << 20);
            w[k] = ew[e];
            bin[k] = b;
            rank[k] = atomicAdd(&cnt[b], 1);
        }
    }
    __syncthreads();
    if (cnt[t] > 0) base[t] = atomicAdd(&gcursor[t], cnt[t]);
    if (cnt[t + 256] > 0) base[t + 256] = atomicAdd(&gcursor[t + 256], cnt[t + 256]);
    __syncthreads();
#pragma unroll
    for (int k = 0; k < FILL_EPT; ++k) {
        if (bin[k] >= 0) {
            int pos = base[bin[k]] + rank[k];
            ebuf[pos] = make_int2(src[k], __float_as_int(w[k]));
        }
    }
}

// per-bucket counting sort -> exact CSR (ebuf2) + row_ptr
__global__ __launch_bounds__(256) void sortB_kernel(const int2* __restrict__ ebuf,
                                                    const int* __restrict__ bstart,
                                                    int2* __restrict__ ebuf2,
                                                    int* __restrict__ row_ptr) {
    __shared__ int cnt[NPB];
    __shared__ int sc[256];
    __shared__ int cur[NPB];
    int t = threadIdx.x, b = blockIdx.x;
    for (int i = t; i < NPB; i += 256) cnt[i] = 0;
    __syncthreads();
    int start = bstart[b], end = bstart[b + 1];
    for (int i = start + t; i < end; i += 256) {
        int dl = ((u32)ebuf[i].x) >> 20;
        atomicAdd(&cnt[dl], 1);
    }
    __syncthreads();
    int own = (t < NPB) ? cnt[t] : 0;
    sc[t] = own;
    __syncthreads();
    for (int off = 1; off < 256; off <<= 1) {
        int v = (t >= off) ? sc[t - off] : 0;
        __syncthreads();
        sc[t] += v;
        __syncthreads();
    }
    int excl = sc[t] - own;
    if (t < NPB) {
        cur[t] = excl;
        int node = b * NPB + t;
        if (node < N_NODES) row_ptr[node] = start + excl;
    }
    if (b == 0 && t == 0) row_ptr[N_NODES] = N_EDGES;
    __syncthreads();
    for (int i = start + t; i < end; i += 256) {
        int2 p = ebuf[i];
        int dl = ((u32)p.x) >> 20;
        int pos = start + atomicAdd(&cur[dl], 1);
        ebuf2[pos] = make_int2(p.x & 0xFFFFF, p.y);
    }
}

// ---------- gemm1 via MFMA: D = W1^T (A) x x^T (B), 16 nodes per wave ----------
__global__ __launch_bounds__(256) void gemm1_kernel(const float* __restrict__ X,
                                                    const float* __restrict__ W,
                                                    u32* __restrict__ Y) {
    __shared__ float Wsh[NFEAT * NHID];  // 32 KB
    int t = threadIdx.x;
    for (int i = t; i < NFEAT * NHID; i += 256) Wsh[i] = W[i];
    __syncthreads();
    int wid = t >> 6;
    int lane = t & 63;
    int r = lane & 15, g = lane >> 4;
    int m0 = (blockIdx.x * 4 + wid) * 16;
    if (m0 >= N_NODES) return;

    bf16x8 af[4][4];  // [ntile][ktile]
#pragma unroll
    for (int nt = 0; nt < 4; ++nt)
#pragma unroll
        for (int kt = 0; kt < 4; ++kt)
#pragma unroll
            for (int j = 0; j < 8; ++j)
                af[nt][kt][j] = f2bf(Wsh[(kt * 32 + g * 8 + j) * NHID + nt * 16 + r]);

    const float* xr = X + (size_t)(m0 + r) * NFEAT + g * 8;
    bf16x8 bfr[4];
#pragma unroll
    for (int kt = 0; kt < 4; ++kt) {
        float4 v0 = *(const float4*)(xr + kt * 32);
        float4 v1 = *(const float4*)(xr + kt * 32 + 4);
        bfr[kt][0] = f2bf(v0.x); bfr[kt][1] = f2bf(v0.y);
        bfr[kt][2] = f2bf(v0.z); bfr[kt][3] = f2bf(v0.w);
        bfr[kt][4] = f2bf(v1.x); bfr[kt][5] = f2bf(v1.y);
        bfr[kt][6] = f2bf(v1.z); bfr[kt][7] = f2bf(v1.w);
    }

    u32* yr = Y + (size_t)(m0 + r) * (NHID / 2);
#pragma unroll
    for (int nt = 0; nt < 4; ++nt) {
        f32x4 acc = {0.f, 0.f, 0.f, 0.f};
#pragma unroll
        for (int kt = 0; kt < 4; ++kt)
            acc = __builtin_amdgcn_mfma_f32_16x16x32_bf16(af[nt][kt], bfr[kt], acc, 0, 0, 0);
        uint2 o;
        o.x = pack_bf16(acc[0], acc[1]);
        o.y = pack_bf16(acc[2], acc[3]);
        *(uint2*)(yr + nt * 8 + g * 2) = o;
    }
}

// ---------- gemm2 via MFMA: D = W2^T x h^T; B-frags load packed-bf16 h directly ----------
__global__ __launch_bounds__(256) void gemm2_kernel(const u32* __restrict__ Hb,
                                                    const float* __restrict__ W,
                                                    u32* __restrict__ Y) {
    __shared__ float Wsh[NHID * NCLASS];  // 4 KB
    int t = threadIdx.x;
    for (int i = t; i < NHID * NCLASS; i += 256) Wsh[i] = W[i];
    __syncthreads();
    int wid = t >> 6;
    int lane = t & 63;
    int r = lane & 15, g = lane >> 4;
    int m0 = (blockIdx.x * 4 + wid) * 16;
    if (m0 >= N_NODES) return;

    bf16x8 af[2];
#pragma unroll
    for (int kt = 0; kt < 2; ++kt)
#pragma unroll
        for (int j = 0; j < 8; ++j)
            af[kt][j] = f2bf(Wsh[(kt * 32 + g * 8 + j) * NCLASS + r]);

    // h row is bf16-packed: u32 idx = feat/2; feats kt*32+g*8+{0..7} -> uint4
    const u32* hr = Hb + (size_t)(m0 + r) * (NHID / 2) + g * 4;
    bf16x8 b0 = *(const bf16x8*)(hr + 0);
    bf16x8 b1 = *(const bf16x8*)(hr + 16);

    f32x4 acc = {0.f, 0.f, 0.f, 0.f};
    acc = __builtin_amdgcn_mfma_f32_16x16x32_bf16(af[0], b0, acc, 0, 0, 0);
    acc = __builtin_amdgcn_mfma_f32_16x16x32_bf16(af[1], b1, acc, 0, 0, 0);

    u32* yr = Y + (size_t)(m0 + r) * (NCLASS / 2);
    uint2 o;
    o.x = pack_bf16(acc[0], acc[1]);
    o.y = pack_bf16(acc[2], acc[3]);
    *(uint2*)(yr + g * 2) = o;
}

// ---------- CSR aggregation (edge-parallel subgroups, no atomics) ----------
// Layer 1: one wave per node; lane = sub*16+p (4 subs); lane gathers uint2
// (4 feats); subs take interleaved edges, 2-deep unroll -> 8 gathers in
// flight; shfl_xor(16,32) reduce; relu + bf16-pack fused into the write.
__global__ __launch_bounds__(256) void agg1_kernel(const u32* __restrict__ xwb,
                                                   const int* __restrict__ row_ptr,
                                                   const int2* __restrict__ ep,
                                                   u32* __restrict__ hb) {
    int t = blockIdx.x * 256 + threadIdx.x;
    int node = t >> 6;
    int lane = t & 63;
    int p = lane & 15;
    int sub = lane >> 4;
    if (node >= N_NODES) return;
    int start = row_ptr[node], end = row_ptr[node + 1];
    float f0 = 0.f, f1 = 0.f, f2 = 0.f, f3 = 0.f;
    float g0 = 0.f, g1 = 0.f, g2 = 0.f, g3 = 0.f;
    int i = start + sub;
    for (; i + 4 < end; i += 8) {
        int2 pa = ep[i];
        int2 pb = ep[i + 4];
        uint2 ua = *(const uint2*)(xwb + (size_t)pa.x * 32 + 2 * p);
        uint2 ub = *(const uint2*)(xwb + (size_t)pb.x * 32 + 2 * p);
        float wa = __int_as_float(pa.y);
        float wb = __int_as_float(pb.y);
        f0 += wa * bf16_lo(ua.x); f1 += wa * bf16_hi(ua.x);
        f2 += wa * bf16_lo(ua.y); f3 += wa * bf16_hi(ua.y);
        g0 += wb * bf16_lo(ub.x); g1 += wb * bf16_hi(ub.x);
        g2 += wb * bf16_lo(ub.y); g3 += wb * bf16_hi(ub.y);
    }
    if (i < end) {
        int2 pa = ep[i];
        uint2 ua = *(const uint2*)(xwb + (size_t)pa.x * 32 + 2 * p);
        float wa = __int_as_float(pa.y);
        f0 += wa * bf16_lo(ua.x); f1 += wa * bf16_hi(ua.x);
        f2 += wa * bf16_lo(ua.y); f3 += wa * bf16_hi(ua.y);
    }
    f0 += g0; f1 += g1; f2 += g2; f3 += g3;
    f0 += __shfl_xor(f0, 16, 64); f1 += __shfl_xor(f1, 16, 64);
    f2 += __shfl_xor(f2, 16, 64); f3 += __shfl_xor(f3, 16, 64);
    f0 += __shfl_xor(f0, 32, 64); f1 += __shfl_xor(f1, 32, 64);
    f2 += __shfl_xor(f2, 32, 64); f3 += __shfl_xor(f3, 32, 64);
    if (sub == 0) {
        uint2 o;
        o.x = pack_bf16(fmaxf(f0, 0.f), fmaxf(f1, 0.f));
        o.y = pack_bf16(fmaxf(f2, 0.f), fmaxf(f3, 0.f));
        *(uint2*)(hb + (size_t)node * 32 + 2 * p) = o;
    }
}

// Layer 2: one wave per node; lane = sub*4+p (16 subs); uint2 gathers from
// the 3.2 MB hwb (L2-resident); shfl_xor(4,8,16,32) reduce; fp32 out.
__global__ __launch_bounds__(256) void agg2_kernel(const u32* __restrict__ hwb,
                                                   const int* __restrict__ row_ptr,
                                                   const int2* __restrict__ ep,
                                                   float* __restrict__ out) {
    int t = blockIdx.x * 256 + threadIdx.x;
    int node = t >> 6;
    int lane = t & 63;
    int p = lane & 3;
    int sub = lane >> 2;
    if (node >= N_NODES) return;
    int start = row_ptr[node], end = row_ptr[node + 1];
    float f0 = 0.f, f1 = 0.f, f2 = 0.f, f3 = 0.f;
    for (int i = start + sub; i < end; i += 16) {
        int2 pr = ep[i];
        uint2 u = *(const uint2*)(hwb + (size_t)pr.x * 8 + 2 * p);
        float w = __int_as_float(pr.y);
        f0 += w * bf16_lo(u.x); f1 += w * bf16_hi(u.x);
        f2 += w * bf16_lo(u.y); f3 += w * bf16_hi(u.y);
    }
    f0 += __shfl_xor(f0, 4, 64);  f1 += __shfl_xor(f1, 4, 64);
    f2 += __shfl_xor(f2, 4, 64);  f3 += __shfl_xor(f3, 4, 64);
    f0 += __shfl_xor(f0, 8, 64);  f1 += __shfl_xor(f1, 8, 64);
    f2 += __shfl_xor(f2, 8, 64);  f3 += __shfl_xor(f3, 8, 64);
    f0 += __shfl_xor(f0, 16, 64); f1 += __shfl_xor(f1, 16, 64);
    f2 += __shfl_xor(f2, 16, 64); f3 += __shfl_xor(f3, 16, 64);
    f0 += __shfl_xor(f0, 32, 64); f1 += __shfl_xor(f1, 32, 64);
    f2 += __shfl_xor(f2, 32, 64); f3 += __shfl_xor(f3, 32, 64);
    if (sub == 0) {
        *(float4*)(out + (size_t)node * NCLASS + 4 * p) = make_float4(f0, f1, f2, f3);
    }
}

extern "C" void kernel_launch(void* const* d_in, const int* in_sizes, int n_in,
                              void* d_out, int out_size, void* d_ws, size_t ws_size,
                              hipStream_t stream) {
    const float* x  = (const float*)d_in[0];
    const void*  ei = d_in[1];
    const float* ew = (const float*)d_in[2];
    const float* W1 = (const float*)d_in[3];
    const float* W2 = (const float*)d_in[4];
    float* out = (float*)d_out;

    char* ws = (char*)d_ws;
    size_t off = 0;
    auto take = [&](size_t bytes) {
        char* p = ws + off;
        off += (bytes + 511) & ~(size_t)511;
        return p;
    };
    int*   flag    = (int*)take(4);
    int*   ghist   = (int*)take(512 * 4);
    int*   bstart  = (int*)take(513 * 4);
    int*   gcursor = (int*)take(512 * 4);
    int*   row_ptr = (int*)take((size_t)(N_NODES + 1) * 4);
    int2*  ebuf    = (int2*)take((size_t)N_EDGES * 8);
    int2*  ebuf2   = (int2*)take((size_t)N_EDGES * 8);
    u32*   xwb     = (u32*)take((size_t)N_NODES * (NHID / 2) * 4);  // bf16 packed
    u32*   hb      = (u32*)take((size_t)N_NODES * (NHID / 2) * 4);  // bf16 packed
    u32*   hwb     = xwb;  // reuse: xwb dead after agg1

    detect_kernel<<<1, 256, 0, stream>>>((const u32*)ei, flag);
    hipMemsetAsync(ghist, 0, 512 * 4, stream);
    histA_kernel<<<HIST_BLOCKS, 256, 0, stream>>>(ei, flag, ghist);
    scanA_kernel<<<1, 512, 0, stream>>>(ghist, bstart, gcursor);
    fillA_kernel<<<FILL_BLOCKS, 256, 0, stream>>>(ei, flag, ew, gcursor, ebuf);
    sortB_kernel<<<NB, 256, 0, stream>>>(ebuf, bstart, ebuf2, row_ptr);

    gemm1_kernel<<<GEMM_BLOCKS, 256, 0, stream>>>(x, W1, xwb);
    agg1_kernel<<<(N_NODES * 64 + 255) / 256, 256, 0, stream>>>(xwb, row_ptr, ebuf2, hb);
    gemm2_kernel<<<GEMM_BLOCKS, 256, 0, stream>>>(hb, W2, hwb);
    agg2_kernel<<<(N_NODES * 64 + 255) / 256, 256, 0, stream>>>(hwb, row_ptr, ebuf2, out);
}